// Round 1
// baseline (474.581 us; speedup 1.0000x reference)
//
#include <hip/hip_runtime.h>
#include <hip/hip_bf16.h>

typedef __attribute__((ext_vector_type(4))) float f32x4;
typedef __attribute__((ext_vector_type(8))) short short8;
typedef unsigned short u16;
typedef unsigned long long u64;

static __device__ __forceinline__ u16 f2bf(float f) {
    __hip_bfloat16 h = __float2bfloat16(f);
    return __builtin_bit_cast(u16, h);
}

// ---------------- degree count ----------------
__global__ void k_deg(const int* __restrict__ dst, int* __restrict__ deg, int E) {
    for (int e = blockIdx.x * blockDim.x + threadIdx.x; e < E; e += gridDim.x * blockDim.x)
        atomicAdd(&deg[dst[e]], 1);
}

// ---------------- 3-kernel exclusive scan over deg[N] ----------------
__global__ void k_scan_a(const int* __restrict__ deg, int* __restrict__ bsum, int n) {
    __shared__ int s[256];
    int tid = threadIdx.x;
    int i = blockIdx.x * 256 + tid;
    s[tid] = (i < n) ? deg[i] : 0;
    __syncthreads();
    for (int ofs = 128; ofs > 0; ofs >>= 1) {
        if (tid < ofs) s[tid] += s[tid + ofs];
        __syncthreads();
    }
    if (tid == 0) bsum[blockIdx.x] = s[0];
}

__global__ void k_scan_b(const int* __restrict__ bsum, int* __restrict__ boff, int nb,
                         int* __restrict__ offN) {
    __shared__ int s[512];
    int tid = threadIdx.x;
    int v = (tid < nb) ? bsum[tid] : 0;
    s[tid] = v;
    __syncthreads();
    for (int ofs = 1; ofs < 512; ofs <<= 1) {
        int t = (tid >= ofs) ? s[tid - ofs] : 0;
        __syncthreads();
        s[tid] += t;
        __syncthreads();
    }
    if (tid < nb) boff[tid] = s[tid] - v;          // exclusive
    if (tid == nb - 1) offN[0] = s[tid];           // total = E
}

__global__ void k_scan_c(const int* __restrict__ deg, const int* __restrict__ boff,
                         int* __restrict__ off, int* __restrict__ cur, int n) {
    __shared__ int s[256];
    int tid = threadIdx.x;
    int i = blockIdx.x * 256 + tid;
    int v = (i < n) ? deg[i] : 0;
    s[tid] = v;
    __syncthreads();
    for (int ofs = 1; ofs < 256; ofs <<= 1) {
        int t = (tid >= ofs) ? s[tid - ofs] : 0;
        __syncthreads();
        s[tid] += t;
        __syncthreads();
    }
    int excl = s[tid] - v + boff[blockIdx.x];
    if (i < n) { off[i] = excl; cur[i] = excl; }
}

// ---------------- CSR fill ----------------
__global__ void k_fill(const int* __restrict__ src, const int* __restrict__ dst,
                       int* __restrict__ cur, int* __restrict__ csr, int E) {
    for (int e = blockIdx.x * blockDim.x + threadIdx.x; e < E; e += gridDim.x * blockDim.x) {
        int d = dst[e];
        int p = atomicAdd(&cur[d], 1);
        csr[p] = src[e];
    }
}

// ---------------- pull-aggregate: aggr[n] = (x[n] + sum_in x[src]) / (deg+1), bf16 out ----------------
__global__ void k_aggr(const float* __restrict__ x, const int* __restrict__ off,
                       const int* __restrict__ csr, u16* __restrict__ aggr, int n) {
    int t = blockIdx.x * blockDim.x + threadIdx.x;
    int g = t >> 5;           // node
    int lane = t & 31;        // float4 slot
    if (g >= n) return;
    const float4* x4 = (const float4*)x;
    size_t rb = (size_t)g * 32 + lane;
    float4 acc = x4[rb];      // self loop
    int s0 = off[g], s1 = off[g + 1];
    int j = s0;
    for (; j + 3 < s1; j += 4) {
        int sa = csr[j], sb = csr[j + 1], sc = csr[j + 2], sd = csr[j + 3];
        float4 va = x4[(size_t)sa * 32 + lane];
        float4 vb = x4[(size_t)sb * 32 + lane];
        float4 vc = x4[(size_t)sc * 32 + lane];
        float4 vd = x4[(size_t)sd * 32 + lane];
        acc.x += va.x + vb.x + vc.x + vd.x;
        acc.y += va.y + vb.y + vc.y + vd.y;
        acc.z += va.z + vb.z + vc.z + vd.z;
        acc.w += va.w + vb.w + vc.w + vd.w;
    }
    for (; j < s1; ++j) {
        int sj = csr[j];
        float4 v = x4[(size_t)sj * 32 + lane];
        acc.x += v.x; acc.y += v.y; acc.z += v.z; acc.w += v.w;
    }
    float inv = 1.0f / (float)(s1 - s0 + 1);
    u16* op = aggr + (size_t)g * 128 + lane * 4;
    ushort4 o;
    o.x = f2bf(acc.x * inv); o.y = f2bf(acc.y * inv);
    o.z = f2bf(acc.z * inv); o.w = f2bf(acc.w * inv);
    *(ushort4*)op = o;
}

// ---------------- fused linear(+bias) + row L2-norm + BN partial sums (MFMA) ----------------
__global__ __launch_bounds__(256, 2) void k_linear(
    const float* __restrict__ x, const u16* __restrict__ aggr,
    const float* __restrict__ W, const float* __restrict__ b_lin,
    float* __restrict__ hout, float* __restrict__ bnsum, float* __restrict__ bnsq,
    int n, int ntiles) {
    // WT[col][k] bf16, 512B per row, byte XOR-swizzle by (col&7)<<4 on the k*2 offset
    __shared__ u16 WT[32768];   // exactly 64 KiB
    int tid = threadIdx.x;

    // stage W (256x128 f32, row-major [k][col]) -> WT bf16 transposed+swizzled
    for (int it = 0; it < 32; ++it) {
        int idx4 = it * 256 + tid;          // 8192 float4s
        int flat = idx4 * 4;
        int k = flat >> 7;
        int c = flat & 127;
        float4 w4 = *(const float4*)(W + flat);
        float wv[4] = {w4.x, w4.y, w4.z, w4.w};
#pragma unroll
        for (int jj = 0; jj < 4; ++jj) {
            int col = c + jj;
            int byteoff = col * 512 + ((2 * k) ^ ((col & 7) << 4));
            *(u16*)((char*)WT + byteoff) = f2bf(wv[jj]);
        }
    }
    __syncthreads();

    int wave = tid >> 6, l = tid & 63, lr = l & 15, lg = l >> 4;
    float s1a[8] = {0, 0, 0, 0, 0, 0, 0, 0};
    float s2a[8] = {0, 0, 0, 0, 0, 0, 0, 0};

    for (int tile = blockIdx.x; tile < ntiles; tile += gridDim.x) {
        int rowA = tile * 64 + wave * 16 + lr;   // A-fragment row this lane supplies
        bool rv = rowA < n;
        f32x4 acc[8];
#pragma unroll
        for (int ct = 0; ct < 8; ++ct) acc[ct] = (f32x4){0.f, 0.f, 0.f, 0.f};

#pragma unroll
        for (int kk = 0; kk < 8; ++kk) {
            int k1 = kk * 32 + 4 * lg;
            short8 av;
            if (kk < 4) {
                float4 fa = rv ? *(const float4*)(x + (size_t)rowA * 128 + k1)
                               : make_float4(0.f, 0.f, 0.f, 0.f);
                float4 fb = rv ? *(const float4*)(x + (size_t)rowA * 128 + k1 + 16)
                               : make_float4(0.f, 0.f, 0.f, 0.f);
                av[0] = (short)f2bf(fa.x); av[1] = (short)f2bf(fa.y);
                av[2] = (short)f2bf(fa.z); av[3] = (short)f2bf(fa.w);
                av[4] = (short)f2bf(fb.x); av[5] = (short)f2bf(fb.y);
                av[6] = (short)f2bf(fb.z); av[7] = (short)f2bf(fb.w);
            } else {
                int ka = k1 - 128;
                const u16* ap = aggr + (size_t)rowA * 128 + ka;
                ushort4 ua = rv ? *(const ushort4*)ap : make_ushort4(0, 0, 0, 0);
                ushort4 ub = rv ? *(const ushort4*)(ap + 16) : make_ushort4(0, 0, 0, 0);
                av[0] = (short)ua.x; av[1] = (short)ua.y; av[2] = (short)ua.z; av[3] = (short)ua.w;
                av[4] = (short)ub.x; av[5] = (short)ub.y; av[6] = (short)ub.z; av[7] = (short)ub.w;
            }
            int kb = 2 * k1;
#pragma unroll
            for (int ct = 0; ct < 8; ++ct) {
                int col = ct * 16 + lr;
                const char* rowp = (const char*)WT + col * 512;
                int mask = (col & 7) << 4;
                u64 lo = *(const u64*)(rowp + (kb ^ mask));
                u64 hi = *(const u64*)(rowp + ((kb + 32) ^ mask));
                union { u64 q[2]; short8 v; } bu;
                bu.q[0] = lo; bu.q[1] = hi;
                acc[ct] = __builtin_amdgcn_mfma_f32_16x16x32_bf16(av, bu.v, acc[ct], 0, 0, 0);
            }
        }

        // epilogue: bias, row L2 norm, store h_norm, BN partials
        int rq0 = tile * 64 + wave * 16 + 4 * lg;   // C rows rq0..rq0+3
        float ss[4] = {0.f, 0.f, 0.f, 0.f};
#pragma unroll
        for (int ct = 0; ct < 8; ++ct) {
            float bl = b_lin[ct * 16 + lr];
#pragma unroll
            for (int q = 0; q < 4; ++q) {
                acc[ct][q] += bl;
                ss[q] += acc[ct][q] * acc[ct][q];
            }
        }
#pragma unroll
        for (int m = 1; m < 16; m <<= 1) {
#pragma unroll
            for (int q = 0; q < 4; ++q) ss[q] += __shfl_xor(ss[q], m, 64);
        }
        float sc[4];
#pragma unroll
        for (int q = 0; q < 4; ++q) sc[q] = 1.0f / fmaxf(sqrtf(ss[q]), 1e-12f);
#pragma unroll
        for (int ct = 0; ct < 8; ++ct) {
            int col = ct * 16 + lr;
            float p1 = 0.f, p2 = 0.f;
#pragma unroll
            for (int q = 0; q < 4; ++q) {
                int r = rq0 + q;
                if (r < n) {
                    float hn = acc[ct][q] * sc[q];
                    hout[(size_t)r * 128 + col] = hn;
                    p1 += hn; p2 += hn * hn;
                }
            }
            s1a[ct] += p1; s2a[ct] += p2;
        }
    }

    // flush BN partials: reduce across the 4 lane-groups, then 1 atomic per col per wave
#pragma unroll
    for (int ct = 0; ct < 8; ++ct) {
        float v1 = s1a[ct], v2 = s2a[ct];
        v1 += __shfl_xor(v1, 16, 64); v1 += __shfl_xor(v1, 32, 64);
        v2 += __shfl_xor(v2, 16, 64); v2 += __shfl_xor(v2, 32, 64);
        if (lg == 0) {
            atomicAdd(&bnsum[ct * 16 + lr], v1);
            atomicAdd(&bnsq[ct * 16 + lr], v2);
        }
    }
}

// ---------------- BN finalize ----------------
__global__ void k_bnfin(const float* __restrict__ bnsum, const float* __restrict__ bnsq,
                        const float* __restrict__ gamma, const float* __restrict__ beta,
                        float* __restrict__ coef, float invN) {
    int c = threadIdx.x;   // 128
    float mu = bnsum[c] * invN;
    float var = bnsq[c] * invN - mu * mu;
    float a = gamma[c] * rsqrtf(var + 1e-5f);
    coef[c] = a;
    coef[128 + c] = beta[c] - mu * a;
}

// ---------------- final: out = relu(hn * a + b2 + x), in-place on hout ----------------
__global__ void k_final(float* __restrict__ hout, const float* __restrict__ x,
                        const float* __restrict__ coef, int total4) {
    const float4* cf4 = (const float4*)coef;
    float4* h4 = (float4*)hout;
    const float4* x4 = (const float4*)x;
    for (int i = blockIdx.x * blockDim.x + threadIdx.x; i < total4; i += gridDim.x * blockDim.x) {
        float4 h = h4[i];
        float4 xv = x4[i];
        int cg = i & 31;
        float4 a4 = cf4[cg];
        float4 b4 = cf4[32 + cg];
        float4 o;
        o.x = fmaxf(h.x * a4.x + b4.x + xv.x, 0.f);
        o.y = fmaxf(h.y * a4.y + b4.y + xv.y, 0.f);
        o.z = fmaxf(h.z * a4.z + b4.z + xv.z, 0.f);
        o.w = fmaxf(h.w * a4.w + b4.w + xv.w, 0.f);
        h4[i] = o;
    }
}

extern "C" void kernel_launch(void* const* d_in, const int* in_sizes, int n_in,
                              void* d_out, int out_size, void* d_ws, size_t ws_size,
                              hipStream_t stream) {
    const float* x     = (const float*)d_in[0];
    const int*   ei    = (const int*)d_in[1];
    const float* W     = (const float*)d_in[3];
    const float* b_lin = (const float*)d_in[4];
    const float* gamma = (const float*)d_in[5];
    const float* beta  = (const float*)d_in[6];
    int N = in_sizes[0] / 128;
    int E = in_sizes[1] / 2;
    const int* src = ei;
    const int* dst = ei + E;

    char* p = (char*)d_ws;
    auto alloc = [&](size_t bytes) { char* r = p; p += (bytes + 255) & ~(size_t)255; return r; };
    int*   deg   = (int*)alloc((size_t)N * 4);
    int*   off   = (int*)alloc((size_t)(N + 1) * 4);
    int*   cur   = (int*)alloc((size_t)N * 4);
    int*   csr   = (int*)alloc((size_t)E * 4);
    int*   bsum  = (int*)alloc(512 * 4);
    int*   boff  = (int*)alloc(512 * 4);
    float* bnsum = (float*)alloc(128 * 4);
    float* bnsq  = (float*)alloc(128 * 4);
    float* coef  = (float*)alloc(256 * 4);
    u16*   aggr  = (u16*)alloc((size_t)N * 128 * 2);

    hipMemsetAsync(deg, 0, (size_t)N * 4, stream);
    hipMemsetAsync(bnsum, 0, 128 * 4, stream);
    hipMemsetAsync(bnsq, 0, 128 * 4, stream);

    k_deg<<<2048, 256, 0, stream>>>(dst, deg, E);
    int nb = (N + 255) / 256;
    k_scan_a<<<nb, 256, 0, stream>>>(deg, bsum, N);
    k_scan_b<<<1, 512, 0, stream>>>(bsum, boff, nb, off + N);
    k_scan_c<<<nb, 256, 0, stream>>>(deg, boff, off, cur, N);
    k_fill<<<2048, 256, 0, stream>>>(src, dst, cur, csr, E);
    k_aggr<<<(int)(((size_t)N * 32 + 255) / 256), 256, 0, stream>>>(x, off, csr, aggr, N);
    int ntiles = (N + 63) / 64;
    k_linear<<<512, 256, 0, stream>>>(x, aggr, W, b_lin, (float*)d_out, bnsum, bnsq, N, ntiles);
    k_bnfin<<<1, 128, 0, stream>>>(bnsum, bnsq, gamma, beta, coef, 1.0f / (float)N);
    k_final<<<2048, 256, 0, stream>>>((float*)d_out, x, coef, N * 32);
}

// Round 2
// 428.945 us; speedup vs baseline: 1.1064x; 1.1064x over previous
//
#include <hip/hip_runtime.h>
#include <hip/hip_bf16.h>

typedef __attribute__((ext_vector_type(4))) float f32x4;
typedef __attribute__((ext_vector_type(8))) short short8;
typedef unsigned short u16;
typedef unsigned long long u64;

static __device__ __forceinline__ u16 f2bf(float f) {
    __hip_bfloat16 h = __float2bfloat16(f);
    return __builtin_bit_cast(u16, h);
}

// ---------------- degree count (int4-vectorized) ----------------
__global__ void k_deg(const int* __restrict__ dst, int* __restrict__ deg, int E) {
    int E4 = E >> 2;
    const int4* d4 = (const int4*)dst;
    int stride = gridDim.x * blockDim.x;
    int gid = blockIdx.x * blockDim.x + threadIdx.x;
    for (int i = gid; i < E4; i += stride) {
        int4 v = d4[i];
        atomicAdd(&deg[v.x], 1);
        atomicAdd(&deg[v.y], 1);
        atomicAdd(&deg[v.z], 1);
        atomicAdd(&deg[v.w], 1);
    }
    for (int e = E4 * 4 + gid; e < E; e += stride)
        atomicAdd(&deg[dst[e]], 1);
}

// ---------------- 3-kernel exclusive scan over deg[N] ----------------
__global__ void k_scan_a(const int* __restrict__ deg, int* __restrict__ bsum, int n) {
    __shared__ int s[256];
    int tid = threadIdx.x;
    int i = blockIdx.x * 256 + tid;
    s[tid] = (i < n) ? deg[i] : 0;
    __syncthreads();
    for (int ofs = 128; ofs > 0; ofs >>= 1) {
        if (tid < ofs) s[tid] += s[tid + ofs];
        __syncthreads();
    }
    if (tid == 0) bsum[blockIdx.x] = s[0];
}

__global__ void k_scan_b(const int* __restrict__ bsum, int* __restrict__ boff, int nb,
                         int* __restrict__ offN) {
    __shared__ int s[512];
    int tid = threadIdx.x;
    int v = (tid < nb) ? bsum[tid] : 0;
    s[tid] = v;
    __syncthreads();
    for (int ofs = 1; ofs < 512; ofs <<= 1) {
        int t = (tid >= ofs) ? s[tid - ofs] : 0;
        __syncthreads();
        s[tid] += t;
        __syncthreads();
    }
    if (tid < nb) boff[tid] = s[tid] - v;          // exclusive
    if (tid == nb - 1) offN[0] = s[tid];           // total = E
}

__global__ void k_scan_c(const int* __restrict__ deg, const int* __restrict__ boff,
                         int* __restrict__ off, int* __restrict__ cur, int n) {
    __shared__ int s[256];
    int tid = threadIdx.x;
    int i = blockIdx.x * 256 + tid;
    int v = (i < n) ? deg[i] : 0;
    s[tid] = v;
    __syncthreads();
    for (int ofs = 1; ofs < 256; ofs <<= 1) {
        int t = (tid >= ofs) ? s[tid - ofs] : 0;
        __syncthreads();
        s[tid] += t;
        __syncthreads();
    }
    int excl = s[tid] - v + boff[blockIdx.x];
    if (i < n) { off[i] = excl; cur[i] = excl; }
}

// ---------------- CSR fill, dst-range grouped for write locality ----------------
// grid.y = NGROUP; group g only handles dst in [g*chunk, (g+1)*chunk): its csr
// window (~E/NGROUP*4 bytes) stays L2-resident -> no scatter write amplification.
__global__ void k_fill(const int* __restrict__ src, const int* __restrict__ dst,
                       int* __restrict__ cur, int* __restrict__ csr, int E, int chunk) {
    int group = blockIdx.y;
    int lo = group * chunk, hi = lo + chunk;
    int E4 = E >> 2;
    const int4* d4 = (const int4*)dst;
    int stride = gridDim.x * blockDim.x;
    int gid = blockIdx.x * blockDim.x + threadIdx.x;
    for (int i = gid; i < E4; i += stride) {
        int4 v = d4[i];
        int e = i * 4;
        if (v.x >= lo && v.x < hi) { int p = atomicAdd(&cur[v.x], 1); csr[p] = src[e]; }
        if (v.y >= lo && v.y < hi) { int p = atomicAdd(&cur[v.y], 1); csr[p] = src[e + 1]; }
        if (v.z >= lo && v.z < hi) { int p = atomicAdd(&cur[v.z], 1); csr[p] = src[e + 2]; }
        if (v.w >= lo && v.w < hi) { int p = atomicAdd(&cur[v.w], 1); csr[p] = src[e + 3]; }
    }
    if (group == 0) {   // tail (E not multiple of 4): unfiltered, group 0 only
        for (int e = E4 * 4 + gid; e < E; e += stride) {
            int d = dst[e];
            int p = atomicAdd(&cur[d], 1);
            csr[p] = src[e];
        }
    }
}

// ---------------- pull-aggregate: one wave per node, 2 edge slots x 32 col lanes ----
__global__ void k_aggr(const float* __restrict__ x, const int* __restrict__ off,
                       const int* __restrict__ csr, u16* __restrict__ aggr, int n) {
    int node = (blockIdx.x * blockDim.x + threadIdx.x) >> 6;
    if (node >= n) return;
    int lane = threadIdx.x & 63;
    int c = lane & 31;    // float4 column slot (16B, 32 slots = 512B row)
    int j = lane >> 5;    // edge slot 0/1
    const float4* x4 = (const float4*)x;
    int s0 = off[node], s1 = off[node + 1];
    float4 acc = make_float4(0.f, 0.f, 0.f, 0.f);
    int e = s0 + j;
    for (; e + 2 < s1; e += 4) {   // 2 rows per slot in flight
        int sa = csr[e], sb = csr[e + 2];
        float4 va = x4[(size_t)sa * 32 + c];
        float4 vb = x4[(size_t)sb * 32 + c];
        acc.x += va.x + vb.x;
        acc.y += va.y + vb.y;
        acc.z += va.z + vb.z;
        acc.w += va.w + vb.w;
    }
    if (e < s1) {
        int sa = csr[e];
        float4 va = x4[(size_t)sa * 32 + c];
        acc.x += va.x; acc.y += va.y; acc.z += va.z; acc.w += va.w;
    }
    acc.x += __shfl_xor(acc.x, 32, 64);
    acc.y += __shfl_xor(acc.y, 32, 64);
    acc.z += __shfl_xor(acc.z, 32, 64);
    acc.w += __shfl_xor(acc.w, 32, 64);
    if (j == 0) {
        float4 sv = x4[(size_t)node * 32 + c];   // self loop
        float inv = 1.0f / (float)(s1 - s0 + 1);
        ushort4 o;
        o.x = f2bf((acc.x + sv.x) * inv);
        o.y = f2bf((acc.y + sv.y) * inv);
        o.z = f2bf((acc.z + sv.z) * inv);
        o.w = f2bf((acc.w + sv.w) * inv);
        *(ushort4*)(aggr + (size_t)node * 128 + c * 4) = o;
    }
}

// ---------------- fused linear(+bias) + row L2-norm + BN partial sums (MFMA) ----------------
__global__ __launch_bounds__(256, 2) void k_linear(
    const float* __restrict__ x, const u16* __restrict__ aggr,
    const float* __restrict__ W, const float* __restrict__ b_lin,
    float* __restrict__ hout, float* __restrict__ bnsum, float* __restrict__ bnsq,
    int n, int ntiles) {
    // WT[col][k] bf16, 512B per row, byte XOR-swizzle by (col&7)<<4 on the k*2 offset
    __shared__ u16 WT[32768];   // exactly 64 KiB
    int tid = threadIdx.x;

    // stage W (256x128 f32, row-major [k][col]) -> WT bf16 transposed+swizzled
    for (int it = 0; it < 32; ++it) {
        int idx4 = it * 256 + tid;          // 8192 float4s
        int flat = idx4 * 4;
        int k = flat >> 7;
        int c = flat & 127;
        float4 w4 = *(const float4*)(W + flat);
        float wv[4] = {w4.x, w4.y, w4.z, w4.w};
#pragma unroll
        for (int jj = 0; jj < 4; ++jj) {
            int col = c + jj;
            int byteoff = col * 512 + ((2 * k) ^ ((col & 7) << 4));
            *(u16*)((char*)WT + byteoff) = f2bf(wv[jj]);
        }
    }
    __syncthreads();

    int wave = tid >> 6, l = tid & 63, lr = l & 15, lg = l >> 4;
    float s1a[8] = {0, 0, 0, 0, 0, 0, 0, 0};
    float s2a[8] = {0, 0, 0, 0, 0, 0, 0, 0};

    for (int tile = blockIdx.x; tile < ntiles; tile += gridDim.x) {
        int rowA = tile * 64 + wave * 16 + lr;   // A-fragment row this lane supplies
        bool rv = rowA < n;
        f32x4 acc[8];
#pragma unroll
        for (int ct = 0; ct < 8; ++ct) acc[ct] = (f32x4){0.f, 0.f, 0.f, 0.f};

#pragma unroll
        for (int kk = 0; kk < 8; ++kk) {
            int k1 = kk * 32 + 4 * lg;
            short8 av;
            if (kk < 4) {
                float4 fa = rv ? *(const float4*)(x + (size_t)rowA * 128 + k1)
                               : make_float4(0.f, 0.f, 0.f, 0.f);
                float4 fb = rv ? *(const float4*)(x + (size_t)rowA * 128 + k1 + 16)
                               : make_float4(0.f, 0.f, 0.f, 0.f);
                av[0] = (short)f2bf(fa.x); av[1] = (short)f2bf(fa.y);
                av[2] = (short)f2bf(fa.z); av[3] = (short)f2bf(fa.w);
                av[4] = (short)f2bf(fb.x); av[5] = (short)f2bf(fb.y);
                av[6] = (short)f2bf(fb.z); av[7] = (short)f2bf(fb.w);
            } else {
                int ka = k1 - 128;
                const u16* ap = aggr + (size_t)rowA * 128 + ka;
                ushort4 ua = rv ? *(const ushort4*)ap : make_ushort4(0, 0, 0, 0);
                ushort4 ub = rv ? *(const ushort4*)(ap + 16) : make_ushort4(0, 0, 0, 0);
                av[0] = (short)ua.x; av[1] = (short)ua.y; av[2] = (short)ua.z; av[3] = (short)ua.w;
                av[4] = (short)ub.x; av[5] = (short)ub.y; av[6] = (short)ub.z; av[7] = (short)ub.w;
            }
            int kb = 2 * k1;
#pragma unroll
            for (int ct = 0; ct < 8; ++ct) {
                int col = ct * 16 + lr;
                const char* rowp = (const char*)WT + col * 512;
                int mask = (col & 7) << 4;
                u64 lo = *(const u64*)(rowp + (kb ^ mask));
                u64 hi = *(const u64*)(rowp + ((kb + 32) ^ mask));
                union { u64 q[2]; short8 v; } bu;
                bu.q[0] = lo; bu.q[1] = hi;
                acc[ct] = __builtin_amdgcn_mfma_f32_16x16x32_bf16(av, bu.v, acc[ct], 0, 0, 0);
            }
        }

        // epilogue: bias, row L2 norm, store h_norm, BN partials
        int rq0 = tile * 64 + wave * 16 + 4 * lg;   // C rows rq0..rq0+3
        float ss[4] = {0.f, 0.f, 0.f, 0.f};
#pragma unroll
        for (int ct = 0; ct < 8; ++ct) {
            float bl = b_lin[ct * 16 + lr];
#pragma unroll
            for (int q = 0; q < 4; ++q) {
                acc[ct][q] += bl;
                ss[q] += acc[ct][q] * acc[ct][q];
            }
        }
#pragma unroll
        for (int m = 1; m < 16; m <<= 1) {
#pragma unroll
            for (int q = 0; q < 4; ++q) ss[q] += __shfl_xor(ss[q], m, 64);
        }
        float sc[4];
#pragma unroll
        for (int q = 0; q < 4; ++q) sc[q] = 1.0f / fmaxf(sqrtf(ss[q]), 1e-12f);
#pragma unroll
        for (int ct = 0; ct < 8; ++ct) {
            int col = ct * 16 + lr;
            float p1 = 0.f, p2 = 0.f;
#pragma unroll
            for (int q = 0; q < 4; ++q) {
                int r = rq0 + q;
                if (r < n) {
                    float hn = acc[ct][q] * sc[q];
                    hout[(size_t)r * 128 + col] = hn;
                    p1 += hn; p2 += hn * hn;
                }
            }
            s1a[ct] += p1; s2a[ct] += p2;
        }
    }

    // flush BN partials: reduce across the 4 lane-groups, then 1 atomic per col per wave
#pragma unroll
    for (int ct = 0; ct < 8; ++ct) {
        float v1 = s1a[ct], v2 = s2a[ct];
        v1 += __shfl_xor(v1, 16, 64); v1 += __shfl_xor(v1, 32, 64);
        v2 += __shfl_xor(v2, 16, 64); v2 += __shfl_xor(v2, 32, 64);
        if (lg == 0) {
            atomicAdd(&bnsum[ct * 16 + lr], v1);
            atomicAdd(&bnsq[ct * 16 + lr], v2);
        }
    }
}

// ---------------- final: BN finalize (per-block, LDS) + out = relu(hn*a + b2 + x) ------
__global__ void k_final(float* __restrict__ hout, const float* __restrict__ x,
                        const float* __restrict__ bnsum, const float* __restrict__ bnsq,
                        const float* __restrict__ gamma, const float* __restrict__ beta,
                        float invN, int total4) {
    __shared__ float coef[256];
    int tid = threadIdx.x;
    if (tid < 128) {
        float mu = bnsum[tid] * invN;
        float var = bnsq[tid] * invN - mu * mu;
        float a = gamma[tid] * rsqrtf(var + 1e-5f);
        coef[tid] = a;
        coef[128 + tid] = beta[tid] - mu * a;
    }
    __syncthreads();
    const float4* cf4 = (const float4*)coef;
    float4* h4 = (float4*)hout;
    const float4* x4 = (const float4*)x;
    for (int i = blockIdx.x * blockDim.x + tid; i < total4; i += gridDim.x * blockDim.x) {
        float4 h = h4[i];
        float4 xv = x4[i];
        int cg = i & 31;
        float4 a4 = cf4[cg];
        float4 b4 = cf4[32 + cg];
        float4 o;
        o.x = fmaxf(h.x * a4.x + b4.x + xv.x, 0.f);
        o.y = fmaxf(h.y * a4.y + b4.y + xv.y, 0.f);
        o.z = fmaxf(h.z * a4.z + b4.z + xv.z, 0.f);
        o.w = fmaxf(h.w * a4.w + b4.w + xv.w, 0.f);
        h4[i] = o;
    }
}

extern "C" void kernel_launch(void* const* d_in, const int* in_sizes, int n_in,
                              void* d_out, int out_size, void* d_ws, size_t ws_size,
                              hipStream_t stream) {
    const float* x     = (const float*)d_in[0];
    const int*   ei    = (const int*)d_in[1];
    const float* W     = (const float*)d_in[3];
    const float* b_lin = (const float*)d_in[4];
    const float* gamma = (const float*)d_in[5];
    const float* beta  = (const float*)d_in[6];
    int N = in_sizes[0] / 128;
    int E = in_sizes[1] / 2;
    const int* src = ei;
    const int* dst = ei + E;

    char* p = (char*)d_ws;
    auto alloc = [&](size_t bytes) { char* r = p; p += (bytes + 255) & ~(size_t)255; return r; };
    // deg, bnsum, bnsq contiguous -> one memset
    int*   deg   = (int*)alloc((size_t)N * 4);
    float* bnsum = (float*)alloc(128 * 4);
    float* bnsq  = (float*)alloc(128 * 4);
    size_t zspan = (char*)(bnsq + 128) - (char*)deg;
    int*   off   = (int*)alloc((size_t)(N + 1) * 4);
    int*   cur   = (int*)alloc((size_t)N * 4);
    int*   csr   = (int*)alloc((size_t)E * 4);
    int*   bsum  = (int*)alloc(512 * 4);
    int*   boff  = (int*)alloc(512 * 4);
    u16*   aggr  = (u16*)alloc((size_t)N * 128 * 2);

    hipMemsetAsync(deg, 0, zspan, stream);

    k_deg<<<1024, 256, 0, stream>>>(dst, deg, E);
    int nb = (N + 255) / 256;
    k_scan_a<<<nb, 256, 0, stream>>>(deg, bsum, N);
    k_scan_b<<<1, 512, 0, stream>>>(bsum, boff, nb, off + N);
    k_scan_c<<<nb, 256, 0, stream>>>(deg, boff, off, cur, N);
    const int NGROUP = 8;
    int chunk = (N + NGROUP - 1) / NGROUP;
    k_fill<<<dim3(256, NGROUP, 1), 256, 0, stream>>>(src, dst, cur, csr, E, chunk);
    k_aggr<<<(int)(((size_t)N * 64 + 255) / 256), 256, 0, stream>>>(x, off, csr, aggr, N);
    int ntiles = (N + 63) / 64;
    k_linear<<<512, 256, 0, stream>>>(x, aggr, W, b_lin, (float*)d_out, bnsum, bnsq, N, ntiles);
    k_final<<<2048, 256, 0, stream>>>((float*)d_out, x, bnsum, bnsq, gamma, beta,
                                      1.0f / (float)N, N * 32);
}